// Round 4
// baseline (309.833 us; speedup 1.0000x reference)
//
#include <hip/hip_runtime.h>

#define DS 256
#define HS 64
#define WS 64
#define BOUT 4
#define NUM 4
#define HO 192
#define WO 192
#define NT 512
#define ROWDW 36               // 72 bf16 per padded row = 36 dwords
#define IMGDW (HS * ROWDW)     // 2304 dwords per image

__device__ __forceinline__ unsigned int f2bf(float f) {
    // round-to-nearest-even f32 -> bf16 (inputs are finite)
    unsigned int u = __float_as_uint(f);
    return (u + 0x7fffu + ((u >> 16) & 1u)) >> 16;
}

__global__ __launch_bounds__(NT, 8)
void mbe_kernel(const float* __restrict__ src,
                const float* __restrict__ flow,
                const float* __restrict__ masks,
                float* __restrict__ out)
{
    __shared__ unsigned int img[NUM * IMGDW];   // 36864 B -> 4 blocks/CU

    const int d  = blockIdx.x;   // channel
    const int bo = blockIdx.y;   // output batch
    const int tid = threadIdx.x;

    // zero the 2-dword pads on each side of every row (4*64 = 256 rows)
    if (tid < NUM * HS) {
        const int n = tid >> 6, row = tid & 63;
        unsigned int* rb = img + n * IMGDW + row * ROWDW;
        *(uint2*)rb        = make_uint2(0u, 0u);
        *(uint2*)(rb + 34) = make_uint2(0u, 0u);
    }

    // stage 4 images, f32 -> packed bf16. slot s: n = s>>9, row = (s>>3)&63, seg = s&7
    #pragma unroll
    for (int l = 0; l < 4; ++l) {
        const int s = l * NT + tid;
        const int n = s >> 9, row = (s >> 3) & 63, seg = s & 7;
        const float* g = src + (((size_t)((n * BOUT + bo) * DS + d)) << 12) + (row << 6) + (seg << 3);
        const float4 a = *(const float4*)g;
        const float4 b = *(const float4*)(g + 4);
        const unsigned int p0 = f2bf(a.x) | (f2bf(a.y) << 16);
        const unsigned int p1 = f2bf(a.z) | (f2bf(a.w) << 16);
        const unsigned int p2 = f2bf(b.x) | (f2bf(b.y) << 16);
        const unsigned int p3 = f2bf(b.z) | (f2bf(b.w) << 16);
        unsigned int* dst = img + n * IMGDW + row * ROWDW + 2 + (seg << 2);
        *(uint2*)dst       = make_uint2(p0, p1);
        *(uint2*)(dst + 2) = make_uint2(p2, p3);
    }
    __syncthreads();

    const size_t obase = ((size_t)bo * DS + d) * (size_t)(HO * WO);

    #pragma unroll 1
    for (int it = 0; it < 8; ++it) {
        const int g  = it * NT + tid;
        const int ys = g >> 6;
        const int xs = g & 63;

        float fy[NUM], fx[NUM], mm[NUM];
        #pragma unroll
        for (int n = 0; n < NUM; ++n) {
            const int b = n * BOUT + bo;
            fy[n] = flow[((size_t)(b * 2 + 0) << 12) + g];
            fx[n] = flow[((size_t)(b * 2 + 1) << 12) + g];
            mm[n] = masks[((size_t)b << 12) + g];
        }

        float acc[3][3];
        #pragma unroll
        for (int j = 0; j < 3; ++j)
            #pragma unroll
            for (int i = 0; i < 3; ++i)
                acc[j][i] = 0.0f;

        #pragma unroll
        for (int n = 0; n < NUM; ++n) {
            const float gy = (float)ys + fy[n];
            const float gx = (float)xs + fx[n];
            const float fiy = floorf(gy);
            const float fix = floorf(gx);
            const int iy = (int)fiy;
            const int ix = (int)fix;
            const float ty = gy - fiy;
            const float tx = gx - fix;

            // x window: cols xb..xb+3; 8-bf16 aligned chunk [c0, c0+8) always covers it
            const int xb = ix - 1;
            int c0 = xb & ~3;
            c0 = min(max(c0, -4), 60);          // stays inside the padded row
            const int r = xb - c0;              // 0..3 when any tap can be valid
            const bool rhi = (r >= 2);
            const unsigned int sh = (unsigned int)((r & 1) << 4);

            // x-lerp weights with validity folded in (invalid tap -> weight 0)
            const float omtx = 1.0f - tx;
            const float A0 = ((unsigned)xb       < (unsigned)WS) ? omtx : 0.0f;
            const float A1 = ((unsigned)(xb + 1) < (unsigned)WS) ? omtx : 0.0f;
            const float A2 = ((unsigned)(xb + 2) < (unsigned)WS) ? omtx : 0.0f;
            const float B0 = ((unsigned)(xb + 1) < (unsigned)WS) ? tx : 0.0f;
            const float B1 = ((unsigned)(xb + 2) < (unsigned)WS) ? tx : 0.0f;
            const float B2 = ((unsigned)(xb + 3) < (unsigned)WS) ? tx : 0.0f;

            // y weights with mask and row validity folded in
            const float wy1 = mm[n] * ty;
            const float wy0 = mm[n] - wy1;
            float WA[3], WB[3];
            #pragma unroll
            for (int j = 0; j < 3; ++j) {
                WA[j] = ((unsigned)(iy - 1 + j) < (unsigned)HS) ? wy0 : 0.0f;
                WB[j] = ((unsigned)(iy + j)     < (unsigned)HS) ? wy1 : 0.0f;
            }

            const unsigned int* imgn = img + n * IMGDW;
            const int cdw = (c0 >> 1) + 2;      // dword offset of chunk in padded row

            #pragma unroll
            for (int rr = 0; rr < 4; ++rr) {
                const int yy = iy - 1 + rr;
                const int yyc = min(max(yy, 0), HS - 1);
                const unsigned int* p = imgn + yyc * ROWDW + cdw;  // 8B-aligned 16B chunk
                const uint2 u01 = *(const uint2*)p;
                const uint2 u23 = *(const uint2*)(p + 2);
                const unsigned int X = rhi ? u01.y : u01.x;
                const unsigned int Y = rhi ? u23.x : u01.y;
                const unsigned int Z = rhi ? u23.y : u23.x;
                const unsigned int A = __builtin_amdgcn_alignbit(Y, X, sh);
                const unsigned int B = __builtin_amdgcn_alignbit(Z, Y, sh);
                const float v0 = __uint_as_float(A << 16);
                const float v1 = __uint_as_float(A & 0xffff0000u);
                const float v2 = __uint_as_float(B << 16);
                const float v3 = __uint_as_float(B & 0xffff0000u);
                const float h0 = v0 * A0 + v1 * B0;
                const float h1 = v1 * A1 + v2 * B1;
                const float h2 = v2 * A2 + v3 * B2;
                // row rr feeds acc[rr] (lower tap) and acc[rr-1] (upper tap)
                if (rr <= 2) {
                    acc[rr][0] += WA[rr] * h0;
                    acc[rr][1] += WA[rr] * h1;
                    acc[rr][2] += WA[rr] * h2;
                }
                if (rr >= 1) {
                    acc[rr - 1][0] += WB[rr - 1] * h0;
                    acc[rr - 1][1] += WB[rr - 1] * h1;
                    acc[rr - 1][2] += WB[rr - 1] * h2;
                }
            }
        }

        #pragma unroll
        for (int j = 0; j < 3; ++j) {
            const int yo = 3 * ys + j;
            #pragma unroll
            for (int i = 0; i < 3; ++i) {
                const int xo = 3 * xs + i;
                out[obase + (size_t)yo * WO + xo] = acc[j][i];
            }
        }
    }
}

extern "C" void kernel_launch(void* const* d_in, const int* in_sizes, int n_in,
                              void* d_out, int out_size, void* d_ws, size_t ws_size,
                              hipStream_t stream) {
    const float* src   = (const float*)d_in[0];
    const float* flow  = (const float*)d_in[1];
    const float* masks = (const float*)d_in[2];
    float* out = (float*)d_out;

    dim3 grid(DS, BOUT);
    mbe_kernel<<<grid, NT, 0, stream>>>(src, flow, masks, out);
}

// Round 5
// 235.661 us; speedup vs baseline: 1.3147x; 1.3147x over previous
//
#include <hip/hip_runtime.h>

#define DS 256
#define HS 64
#define WS 64
#define BOUT 4
#define NUM 4
#define HO 192
#define WO 192
#define NT 512
#define ROWDW 36               // 72 bf16 per padded row = 36 dwords
#define IMGDW (HS * ROWDW)     // 2304 dwords per image

__device__ __forceinline__ unsigned int f2bf(float f) {
    // round-to-nearest-even f32 -> bf16 (inputs are finite)
    unsigned int u = __float_as_uint(f);
    return (u + 0x7fffu + ((u >> 16) & 1u)) >> 16;
}

__global__ __launch_bounds__(NT, 4)
void mbe_kernel(const float* __restrict__ src,
                const float* __restrict__ flow,
                const float* __restrict__ masks,
                float* __restrict__ out)
{
    __shared__ unsigned int img[NUM * IMGDW];   // 36864 B -> 4 blocks/CU

    const int d  = blockIdx.x;   // channel
    const int bo = blockIdx.y;   // output batch
    const int tid = threadIdx.x;

    // zero the 2-dword pads on each side of every row (4*64 = 256 rows)
    if (tid < NUM * HS) {
        const int n = tid >> 6, row = tid & 63;
        unsigned int* rb = img + n * IMGDW + row * ROWDW;
        *(uint2*)rb        = make_uint2(0u, 0u);
        *(uint2*)(rb + 34) = make_uint2(0u, 0u);
    }

    // stage 4 images, f32 -> packed bf16. slot s: n = s>>9, row = (s>>3)&63, seg = s&7
    #pragma unroll
    for (int l = 0; l < 4; ++l) {
        const int s = l * NT + tid;
        const int n = s >> 9, row = (s >> 3) & 63, seg = s & 7;
        const float* g = src + (((size_t)((n * BOUT + bo) * DS + d)) << 12) + (row << 6) + (seg << 3);
        const float4 a = *(const float4*)g;
        const float4 b = *(const float4*)(g + 4);
        const unsigned int p0 = f2bf(a.x) | (f2bf(a.y) << 16);
        const unsigned int p1 = f2bf(a.z) | (f2bf(a.w) << 16);
        const unsigned int p2 = f2bf(b.x) | (f2bf(b.y) << 16);
        const unsigned int p3 = f2bf(b.z) | (f2bf(b.w) << 16);
        unsigned int* dst = img + n * IMGDW + row * ROWDW + 2 + (seg << 2);
        *(uint2*)dst       = make_uint2(p0, p1);
        *(uint2*)(dst + 2) = make_uint2(p2, p3);
    }
    __syncthreads();

    const size_t obase = ((size_t)bo * DS + d) * (size_t)(HO * WO);

    #pragma unroll 1
    for (int it = 0; it < 8; ++it) {
        const int g  = it * NT + tid;
        const int ys = g >> 6;
        const int xs = g & 63;

        float fy[NUM], fx[NUM], mm[NUM];
        #pragma unroll
        for (int n = 0; n < NUM; ++n) {
            const int b = n * BOUT + bo;
            fy[n] = flow[((size_t)(b * 2 + 0) << 12) + g];
            fx[n] = flow[((size_t)(b * 2 + 1) << 12) + g];
            mm[n] = masks[((size_t)b << 12) + g];
        }

        float acc[3][3];
        #pragma unroll
        for (int j = 0; j < 3; ++j)
            #pragma unroll
            for (int i = 0; i < 3; ++i)
                acc[j][i] = 0.0f;

        #pragma unroll
        for (int n = 0; n < NUM; ++n) {
            const float gy = (float)ys + fy[n];
            const float gx = (float)xs + fx[n];
            const float fiy = floorf(gy);
            const float fix = floorf(gx);
            const int iy = (int)fiy;
            const int ix = (int)fix;
            const float ty = gy - fiy;
            const float tx = gx - fix;

            // x window: cols xb..xb+3; 8-bf16 aligned chunk [c0, c0+8) always covers it
            const int xb = ix - 1;
            int c0 = xb & ~3;
            c0 = min(max(c0, -4), 60);          // stays inside the padded row
            const int r = xb - c0;              // 0..3 when any tap can be valid
            const bool rhi = (r >= 2);
            const unsigned int sh = (unsigned int)((r & 1) << 4);

            // x-lerp weights with validity folded in (invalid tap -> weight 0)
            const float omtx = 1.0f - tx;
            const float A0 = ((unsigned)xb       < (unsigned)WS) ? omtx : 0.0f;
            const float A1 = ((unsigned)(xb + 1) < (unsigned)WS) ? omtx : 0.0f;
            const float A2 = ((unsigned)(xb + 2) < (unsigned)WS) ? omtx : 0.0f;
            const float B0 = ((unsigned)(xb + 1) < (unsigned)WS) ? tx : 0.0f;
            const float B1 = ((unsigned)(xb + 2) < (unsigned)WS) ? tx : 0.0f;
            const float B2 = ((unsigned)(xb + 3) < (unsigned)WS) ? tx : 0.0f;

            // y weights with mask and row validity folded in
            const float wy1 = mm[n] * ty;
            const float wy0 = mm[n] - wy1;
            float WA[3], WB[3];
            #pragma unroll
            for (int j = 0; j < 3; ++j) {
                WA[j] = ((unsigned)(iy - 1 + j) < (unsigned)HS) ? wy0 : 0.0f;
                WB[j] = ((unsigned)(iy + j)     < (unsigned)HS) ? wy1 : 0.0f;
            }

            const unsigned int* imgn = img + n * IMGDW;
            const int cdw = (c0 >> 1) + 2;      // dword offset of chunk in padded row

            #pragma unroll
            for (int rr = 0; rr < 4; ++rr) {
                const int yy = iy - 1 + rr;
                const int yyc = min(max(yy, 0), HS - 1);
                const unsigned int* p = imgn + yyc * ROWDW + cdw;  // 8B-aligned 16B chunk
                const uint2 u01 = *(const uint2*)p;
                const uint2 u23 = *(const uint2*)(p + 2);
                const unsigned int X = rhi ? u01.y : u01.x;
                const unsigned int Y = rhi ? u23.x : u01.y;
                const unsigned int Z = rhi ? u23.y : u23.x;
                const unsigned int A = __builtin_amdgcn_alignbit(Y, X, sh);
                const unsigned int B = __builtin_amdgcn_alignbit(Z, Y, sh);
                const float v0 = __uint_as_float(A << 16);
                const float v1 = __uint_as_float(A & 0xffff0000u);
                const float v2 = __uint_as_float(B << 16);
                const float v3 = __uint_as_float(B & 0xffff0000u);
                const float h0 = v0 * A0 + v1 * B0;
                const float h1 = v1 * A1 + v2 * B1;
                const float h2 = v2 * A2 + v3 * B2;
                // row rr feeds acc[rr] (lower tap) and acc[rr-1] (upper tap)
                if (rr <= 2) {
                    acc[rr][0] += WA[rr] * h0;
                    acc[rr][1] += WA[rr] * h1;
                    acc[rr][2] += WA[rr] * h2;
                }
                if (rr >= 1) {
                    acc[rr - 1][0] += WB[rr - 1] * h0;
                    acc[rr - 1][1] += WB[rr - 1] * h1;
                    acc[rr - 1][2] += WB[rr - 1] * h2;
                }
            }
        }

        #pragma unroll
        for (int j = 0; j < 3; ++j) {
            const int yo = 3 * ys + j;
            #pragma unroll
            for (int i = 0; i < 3; ++i) {
                const int xo = 3 * xs + i;
                out[obase + (size_t)yo * WO + xo] = acc[j][i];
            }
        }
    }
}

extern "C" void kernel_launch(void* const* d_in, const int* in_sizes, int n_in,
                              void* d_out, int out_size, void* d_ws, size_t ws_size,
                              hipStream_t stream) {
    const float* src   = (const float*)d_in[0];
    const float* flow  = (const float*)d_in[1];
    const float* masks = (const float*)d_in[2];
    float* out = (float*)d_out;

    dim3 grid(DS, BOUT);
    mbe_kernel<<<grid, NT, 0, stream>>>(src, flow, masks, out);
}

// Round 7
// 233.015 us; speedup vs baseline: 1.3297x; 1.0114x over previous
//
#include <hip/hip_runtime.h>

#define DS 256
#define HS 64
#define WS 64
#define BOUT 4
#define NUM 4
#define HO 192
#define WO 192
#define NT 512
#define ROWDW 37               // dwords per padded row: cols -4..69 (2 pad + 32 data + 3 pad)
#define IMGDW (HS * ROWDW)     // 2368 dwords per image plane

__device__ __forceinline__ unsigned int f2bf(float f) {
    // round-to-nearest-even f32 -> bf16 (inputs are finite)
    unsigned int u = __float_as_uint(f);
    return (u + 0x7fffu + ((u >> 16) & 1u)) >> 16;
}

__global__ __launch_bounds__(NT, 4)
void mbe_kernel(const float* __restrict__ src,
                const float* __restrict__ flow,
                const float* __restrict__ masks,
                float* __restrict__ out)
{
    __shared__ unsigned int img[NUM * IMGDW];   // 37888 B -> 4 blocks/CU

    const int d  = blockIdx.x;   // channel
    const int bo = blockIdx.y;   // output batch
    const int tid = threadIdx.x;

    // ---- zero the pad dwords {0,1,34,35,36} of every row (semantic zeros) ----
    // 4 planes * 64 rows * 5 pad dwords = 1280 stores (disjoint from data region)
    for (int idx = tid; idx < NUM * HS * 5; idx += NT) {
        const int n   = idx / (HS * 5);
        const int r   = idx - n * (HS * 5);
        const int row = r / 5;
        const int c5  = r - row * 5;
        const int dw  = (c5 < 2) ? c5 : (c5 + 32);
        img[n * IMGDW + row * ROWDW + dw] = 0u;
    }

    // ---- stage 4 images, f32 -> packed bf16 (data dwords 2..33 of each row) ----
    #pragma unroll
    for (int l = 0; l < 4; ++l) {
        const int s = l * NT + tid;
        const int n = s >> 9, row = (s >> 3) & 63, seg = s & 7;
        const float* g = src + (((size_t)((n * BOUT + bo) * DS + d)) << 12) + (row << 6) + (seg << 3);
        const float4 a = *(const float4*)g;
        const float4 b = *(const float4*)(g + 4);
        const unsigned int p0 = f2bf(a.x) | (f2bf(a.y) << 16);
        const unsigned int p1 = f2bf(a.z) | (f2bf(a.w) << 16);
        const unsigned int p2 = f2bf(b.x) | (f2bf(b.y) << 16);
        const unsigned int p3 = f2bf(b.z) | (f2bf(b.w) << 16);
        // dword index parity varies (37*row) -> 4B alignment only: scalar stores (merge to ds_write2_b32)
        unsigned int* dst = img + n * IMGDW + row * ROWDW + 2 + (seg << 2);
        dst[0] = p0; dst[1] = p1; dst[2] = p2; dst[3] = p3;
    }
    __syncthreads();

    const size_t obase = ((size_t)bo * DS + d) * (size_t)(HO * WO);

    #pragma unroll 1
    for (int it = 0; it < 8; ++it) {
        const int g  = it * NT + tid;
        const int ys = g >> 6;
        const int xs = g & 63;

        float fy[NUM], fx[NUM], mm[NUM];
        #pragma unroll
        for (int n = 0; n < NUM; ++n) {
            const int b = n * BOUT + bo;
            fy[n] = flow[((size_t)(b * 2 + 0) << 12) + g];
            fx[n] = flow[((size_t)(b * 2 + 1) << 12) + g];
            mm[n] = masks[((size_t)b << 12) + g];
        }

        float acc[3][3];
        #pragma unroll
        for (int j = 0; j < 3; ++j)
            #pragma unroll
            for (int i = 0; i < 3; ++i)
                acc[j][i] = 0.0f;

        #pragma unroll
        for (int n = 0; n < NUM; ++n) {
            const float gy = (float)ys + fy[n];
            // clamp x into the padded window range; outside (-3,66) every tap is a
            // semantic zero, and the clamp preserves exact sampling for any gx that
            // has at least one valid tap.
            const float gxc = __builtin_amdgcn_fmed3f((float)xs + fx[n], -3.0f, 66.0f);

            const float fix = floorf(gxc);
            const int   ix  = (int)fix;
            const float tx  = gxc - fix;
            const int   xb  = ix - 1;                       // [-4, 65]
            const unsigned int sh = (unsigned int)((xb & 1) << 4);
            const int   cdw = (xb >> 1) + 2;                // [0, 34]; reads cdw..cdw+2 <= 36

            const float fiy = floorf(gy);
            const int   iy  = (int)fiy;
            const float ty  = gy - fiy;

            // y weights with mask and row validity folded in
            const float wy1 = mm[n] * ty;
            const float wy0 = mm[n] - wy1;
            float WA[3], WB[3];
            #pragma unroll
            for (int j = 0; j < 3; ++j) {
                WA[j] = ((unsigned)(iy - 1 + j) < (unsigned)HS) ? wy0 : 0.0f;
                WB[j] = ((unsigned)(iy + j)     < (unsigned)HS) ? wy1 : 0.0f;
            }

            const unsigned int* imgn = img + n * IMGDW;

            #pragma unroll
            for (int rr = 0; rr < 4; ++rr) {
                const int yy  = iy - 1 + rr;
                const int yyc = min(max(yy, 0), HS - 1);    // weight 0 rows read real (finite) data
                const unsigned int* p = imgn + yyc * ROWDW + cdw;
                const unsigned int X = p[0];
                const unsigned int Y = p[1];
                const unsigned int Z = p[2];
                const unsigned int A = __builtin_amdgcn_alignbit(Y, X, sh);
                const unsigned int B = __builtin_amdgcn_alignbit(Z, Y, sh);
                const float v0 = __uint_as_float(A << 16);
                const float v1 = __uint_as_float(A & 0xffff0000u);
                const float v2 = __uint_as_float(B << 16);
                const float v3 = __uint_as_float(B & 0xffff0000u);
                // x-lerp; OOB taps are exact zeros from the pads
                const float h0 = v0 + tx * (v1 - v0);
                const float h1 = v1 + tx * (v2 - v1);
                const float h2 = v2 + tx * (v3 - v2);
                if (rr <= 2) {
                    acc[rr][0] += WA[rr] * h0;
                    acc[rr][1] += WA[rr] * h1;
                    acc[rr][2] += WA[rr] * h2;
                }
                if (rr >= 1) {
                    acc[rr - 1][0] += WB[rr - 1] * h0;
                    acc[rr - 1][1] += WB[rr - 1] * h1;
                    acc[rr - 1][2] += WB[rr - 1] * h2;
                }
            }
        }

        #pragma unroll
        for (int j = 0; j < 3; ++j) {
            const int yo = 3 * ys + j;
            #pragma unroll
            for (int i = 0; i < 3; ++i) {
                const int xo = 3 * xs + i;
                out[obase + (size_t)yo * WO + xo] = acc[j][i];
            }
        }
    }
}

extern "C" void kernel_launch(void* const* d_in, const int* in_sizes, int n_in,
                              void* d_out, int out_size, void* d_ws, size_t ws_size,
                              hipStream_t stream) {
    const float* src   = (const float*)d_in[0];
    const float* flow  = (const float*)d_in[1];
    const float* masks = (const float*)d_in[2];
    float* out = (float*)d_out;

    dim3 grid(DS, BOUT);
    mbe_kernel<<<grid, NT, 0, stream>>>(src, flow, masks, out);
}